// Round 11
// baseline (1506.216 us; speedup 1.0000x reference)
//
#include <hip/hip_runtime.h>
#include <hip/hip_bf16.h>

#define N_NODES 100000
#define N_EDGES 800000

typedef __attribute__((ext_vector_type(8))) short short8v;   // 8 bf16 = 4 VGPRs
typedef __attribute__((ext_vector_type(4))) float f32x4;

__device__ __forceinline__ unsigned short f2bf(float f) {
    __hip_bfloat16 b = __float2bfloat16(f);
    return *(unsigned short*)&b;
}
__device__ __forceinline__ float bf2f(unsigned short u) {
    return __uint_as_float((unsigned)u << 16);
}
__device__ __forceinline__ unsigned pack2(float lo, float hi) {
    return (unsigned)f2bf(lo) | ((unsigned)f2bf(hi) << 16);
}

// async 16B global->LDS DMA (gfx950). LDS dest: wave-uniform base + lane*16.
__device__ __forceinline__ void gload_lds16(const void* g, void* l) {
    __builtin_amdgcn_global_load_lds(
        (const __attribute__((address_space(1))) unsigned int*)g,
        (__attribute__((address_space(3))) unsigned int*)l,
        16, 0, 0);
}

// bijective XCD-chunked block swizzle (m204).
__device__ __forceinline__ int xcd_swizzle(int orig, int q, int r) {
    int xcd = orig & 7, loc = orig >> 3;
    return (xcd < r ? xcd * (q + 1) : r * (q + 1) + (xcd - r) * q) + loc;
}

// ---------- CSR build ----------
__global__ __launch_bounds__(256) void hist_dst(
    const int* __restrict__ dst, int* __restrict__ counts)
{
    int e = blockIdx.x * 256 + threadIdx.x;
    if (e < N_EDGES) atomicAdd(&counts[dst[e]], 1);
}

__global__ __launch_bounds__(256) void scan_p1(
    const int* __restrict__ in, int* __restrict__ partials, int n)
{
    __shared__ int ws[4];
    int t = threadIdx.x, lane = t & 63, wv = t >> 6;
    int base = blockIdx.x * 1024;
    int s = 0;
#pragma unroll
    for (int i = 0; i < 4; ++i) {
        int idx = base + i * 256 + t;
        s += (idx < n) ? in[idx] : 0;
    }
#pragma unroll
    for (int off = 1; off < 64; off <<= 1) s += __shfl_xor(s, off);
    if (lane == 0) ws[wv] = s;
    __syncthreads();
    if (t == 0) partials[blockIdx.x] = ws[0] + ws[1] + ws[2] + ws[3];
}

__global__ __launch_bounds__(64) void scan_p2(
    int* __restrict__ partials, int nb, int* __restrict__ total_out)
{
    int lane = threadIdx.x;
    int carry = 0;
    for (int base = 0; base < nb; base += 64) {
        int idx = base + lane;
        int v = (idx < nb) ? partials[idx] : 0;
        int s = v;
#pragma unroll
        for (int off = 1; off < 64; off <<= 1) {
            int w = __shfl_up(s, off);
            if (lane >= off) s += w;
        }
        if (idx < nb) partials[idx] = s - v + carry;
        carry += __shfl(s, 63);
    }
    if (lane == 0) *total_out = carry;
}

__global__ __launch_bounds__(256) void scan_p3(
    const int* __restrict__ in, int* __restrict__ out, int* __restrict__ cursor,
    const int* __restrict__ partials, int n)
{
    __shared__ int ws[4];
    __shared__ int wpre[4];
    __shared__ int s_tot;
    int t = threadIdx.x, lane = t & 63, wv = t >> 6;
    int base = blockIdx.x * 1024;
    int carry = partials[blockIdx.x];
    for (int sub = 0; sub < 4; ++sub) {
        int idx = base + sub * 256 + t;
        int v = (idx < n) ? in[idx] : 0;
        int s = v;
#pragma unroll
        for (int off = 1; off < 64; off <<= 1) {
            int w = __shfl_up(s, off);
            if (lane >= off) s += w;
        }
        if (lane == 63) ws[wv] = s;
        __syncthreads();
        if (t == 0) {
            int a = 0;
#pragma unroll
            for (int i = 0; i < 4; ++i) { wpre[i] = a; a += ws[i]; }
            s_tot = a;
        }
        __syncthreads();
        int excl = s - v + wpre[wv] + carry;
        if (idx < n) { out[idx] = excl; if (cursor) cursor[idx] = excl; }
        carry += s_tot;
        __syncthreads();
    }
}

__global__ __launch_bounds__(256) void scatter_edges(
    const int* __restrict__ dst, const int* __restrict__ src,
    int* __restrict__ cursor,
    int* __restrict__ edge_ord, int* __restrict__ src_ord,
    int* __restrict__ dst_ord)
{
    int e = blockIdx.x * 256 + threadIdx.x;
    if (e < N_EDGES) {
        int d = dst[e];
        int pos = atomicAdd(&cursor[d], 1);
        edge_ord[pos] = e;
        src_ord[pos] = src[e];
        dst_ord[pos] = d;
    }
}

// npieces[n] = number of 64-slot blocks node n's slot range touches
__global__ __launch_bounds__(256) void calc_npieces(
    const int* __restrict__ offsets, int* __restrict__ npieces)
{
    int n = blockIdx.x * 256 + threadIdx.x;
    if (n < N_NODES) {
        int b = offsets[n], e = offsets[n + 1];
        npieces[n] = (e > b) ? (((e - 1) >> 6) - (b >> 6) + 1) : 0;
    }
}

// ---------- fused weight prep: w3t,w5t | wcatt | mw1t,mw2t ----------
__global__ __launch_bounds__(256) void prep_weights(
    const float* __restrict__ W1, const float* __restrict__ W2,
    const float* __restrict__ W3, const float* __restrict__ W4,
    const float* __restrict__ W5, const float* __restrict__ W6,
    const float* __restrict__ mw1, const float* __restrict__ mw2,
    unsigned short* __restrict__ w3t, unsigned short* __restrict__ w5t,
    unsigned short* __restrict__ wcatt,
    unsigned short* __restrict__ mw1t, unsigned short* __restrict__ mw2t)
{
    int bid = blockIdx.x;
    if (bid < 64) {
        int t = bid * 256 + threadIdx.x;          // 0..16383
        int r = t >> 7, c = t & 127;
        w3t[c * 128 + r] = f2bf(W3[t]);
        w5t[c * 128 + r] = f2bf(W5[t]);
    } else if (bid < 320) {
        int t = (bid - 64) * 256 + threadIdx.x;   // 0..65535
        int n = t >> 7, k = t & 127;
        const float* Wm = (n < 128) ? W1 : (n < 256) ? W2 : (n < 384) ? W4 : W6;
        wcatt[t] = f2bf(Wm[k * 128 + (n & 127)]);
    } else {
        int t = (bid - 320) * 256 + threadIdx.x;  // 0..65535
        if (t < 32768) {
            int n = t >> 7, k = t & 127;
            mw1t[t] = f2bf(mw1[k * 256 + n]);
        } else {
            int s = t - 32768;
            int n = s >> 8, k = s & 255;
            mw2t[s] = f2bf(mw2[k * 128 + n]);
        }
    }
}

// ---------- node GEMM: [u|v|k] bf16 + hw6 f32 = h(f32) @ [W1|W2|W4|W6] ----------
__global__ __launch_bounds__(256) void gemm_node(
    const float* __restrict__ A, const unsigned short* __restrict__ Bt,
    unsigned short* __restrict__ uvkb, float* __restrict__ hw6f)
{
    const int t = threadIdx.x;
    const int lane = t & 63, wv = t >> 6;
    const int l15 = lane & 15, kg = lane >> 4;
    const int m0 = blockIdx.x * 64;
    const int n0 = blockIdx.y * 128;
    const int M = N_NODES, K = 128;

    int arow = m0 + wv * 16 + l15;
    int arow_c = arow < M ? arow : M - 1;
    const float* ap = A + (size_t)arow_c * K + kg * 8;

    f32x4 acc[8];
#pragma unroll
    for (int nt = 0; nt < 8; ++nt) acc[nt] = (f32x4){0.f, 0.f, 0.f, 0.f};

    for (int ko = 0; ko < K; ko += 32) {
        float4 f0 = *(const float4*)(ap + ko);
        float4 f1 = *(const float4*)(ap + ko + 4);
        short8v af;
        af[0] = (short)f2bf(f0.x); af[1] = (short)f2bf(f0.y);
        af[2] = (short)f2bf(f0.z); af[3] = (short)f2bf(f0.w);
        af[4] = (short)f2bf(f1.x); af[5] = (short)f2bf(f1.y);
        af[6] = (short)f2bf(f1.z); af[7] = (short)f2bf(f1.w);
#pragma unroll
        for (int nt = 0; nt < 8; ++nt) {
            short8v bf = *(const short8v*)(Bt + (size_t)(n0 + nt * 16 + l15) * K + ko + kg * 8);
            acc[nt] = __builtin_amdgcn_mfma_f32_16x16x32_bf16(af, bf, acc[nt], 0, 0, 0);
        }
    }
#pragma unroll
    for (int nt = 0; nt < 8; ++nt) {
#pragma unroll
        for (int r = 0; r < 4; ++r) {
            int row = m0 + wv * 16 + kg * 4 + r;
            if (row < M) {
                int col = n0 + nt * 16 + l15;
                float vfl = acc[nt][r];
                if (n0 < 384) uvkb[(size_t)row * 384 + col] = f2bf(vfl);
                else          hw6f[(size_t)row * 128 + col - 384] = vfl;
            }
        }
    }
}

// ---------- fused edge pass + in-register segmented aggregation ----------
// v24: SPLIT-K staging for 8-block/CU residency at the SAME 64-edge tile.
// The e-tile is staged in two column halves (cols 0-63, 64-127) through one
// 16 KB f32 buffer (bf16 conversion in place, 8 KB); the K-pass accumulates
// across halves (MFMA acc is K-order-independent). LDS ~18 KB -> 8 blocks x
// 4 waves = 32 waves/CU (was 4 blocks / 43% occ -- the LDS cap). Traffic is
// IDENTICAL to v19/v23 (same tile, same pieces -- round-7's amplification
// trap avoided). 9 barriers/block, covered by 8-way block interleave.
__global__ __launch_bounds__(256, 8) void edge_agg(
    const float* __restrict__ e_ij,
    const unsigned short* __restrict__ w3t, const unsigned short* __restrict__ w5t,
    const unsigned short* __restrict__ uvkb,
    const int* __restrict__ edge_ord, const int* __restrict__ src_ord,
    const int* __restrict__ dst_ord,
    const int* __restrict__ offsets, const int* __restrict__ ppos,
    float* __restrict__ dpart, float* __restrict__ apart)
{
    __shared__ __align__(16) float e_s[64 * 64];    // 16 KB f32 half-tile; first 8 KB reused bf16
    __shared__ int s_eid[64], s_src[64], s_dst[64];
    __shared__ int s_sb[64], s_se[64], s_pi[64];
    __shared__ int s_nseg;

    const int t  = threadIdx.x;
    const int lane = t & 63, wv = t >> 6;
    const int l15 = lane & 15, kg = lane >> 4;
    const int cb = wv * 32 + 2 * l15;              // this lane's col pair
    const float inv = 0.17677669529663687f;        // 1/sqrt(32)

    const int nwg = N_EDGES / 64;                  // 12500
    const int bswz = xcd_swizzle((int)blockIdx.x, nwg >> 3, nwg & 7);
    const int e0 = bswz * 64;

    // ---- meta: wave 0 ballots segments ----
    if (t < 64) {
        s_eid[t] = edge_ord[e0 + t];
        s_src[t] = src_ord[e0 + t];
        int d = dst_ord[e0 + t];
        s_dst[t] = d;
        int dprev = __shfl_up(d, 1);
        bool bnd = (t == 0) || (d != dprev);
        unsigned long long mask = __ballot(bnd);
        int sid = __popcll(mask & ((1ull << t) - 1ull));
        if (bnd) {
            s_sb[sid] = t;
            s_pi[sid] = ppos[d] + bswz - (offsets[d] >> 6);
            if (t > 0) s_se[sid - 1] = t;
        }
        if (t == 63) {
            int ns = __popcll(mask);
            s_se[ns - 1] = 64;
            s_nseg = ns;
        }
    }
    __syncthreads();

    f32x4 a3[4][2], a5[4][2];
#pragma unroll
    for (int m = 0; m < 4; ++m) {
        a3[m][0] = (f32x4){0.f, 0.f, 0.f, 0.f};
        a3[m][1] = (f32x4){0.f, 0.f, 0.f, 0.f};
        a5[m][0] = (f32x4){0.f, 0.f, 0.f, 0.f};
        a5[m][1] = (f32x4){0.f, 0.f, 0.f, 0.f};
    }
    const unsigned short* b3p0 = w3t + (size_t)(cb + 0) * 128 + kg * 8;
    const unsigned short* b3p1 = w3t + (size_t)(cb + 1) * 128 + kg * 8;
    const unsigned short* b5p0 = w5t + (size_t)(cb + 0) * 128 + kg * 8;
    const unsigned short* b5p1 = w5t + (size_t)(cb + 1) * 128 + kg * 8;
    unsigned short* eb = (unsigned short*)&e_s[0];  // bf16 [64][64] half; chunk c at c^(row&7)

    for (int half = 0; half < 2; ++half) {
        // ---- async DMA: 1024 chunks of 16B (64 rows x 16 f32-chunks).
        // LDS f32 chunk (row, j) receives global chunk j^(row&7) of this half.
#pragma unroll
        for (int i = 0; i < 4; ++i) {
            int c = i * 256 + t;
            int row = c >> 4, j = c & 15;
            int js = j ^ (row & 7);
            const float* g = e_ij + (size_t)s_eid[row] * 128 + half * 64 + js * 4;
            void* l = (void*)((char*)(&e_s[0]) + (size_t)i * 4096 + (size_t)wv * 1024);
            gload_lds16(g, l);
        }
        __syncthreads();   // drain: f32 half staged

        // ---- shared conversion: f32 half -> bf16 (in place, first 8 KB).
        // thread t: row = t>>2, quarter q = t&3 -> local f32 elems [q*16,q*16+16)
        {
            const int crow = t >> 2, q = t & 3;
            float4 fr[4];
#pragma unroll
            for (int i = 0; i < 4; ++i) {
                int p = (q * 4 + i) ^ (crow & 7);   // stored (swizzled) f32 chunk pos
                fr[i] = *(const float4*)(&e_s[crow * 64 + p * 4]);
            }
            __syncthreads();   // all f32 reads complete before bf16 writes clobber
#pragma unroll
            for (int i = 0; i < 2; ++i) {
                short8v pk;
                pk[0] = (short)f2bf(fr[2 * i].x);     pk[1] = (short)f2bf(fr[2 * i].y);
                pk[2] = (short)f2bf(fr[2 * i].z);     pk[3] = (short)f2bf(fr[2 * i].w);
                pk[4] = (short)f2bf(fr[2 * i + 1].x); pk[5] = (short)f2bf(fr[2 * i + 1].y);
                pk[6] = (short)f2bf(fr[2 * i + 1].z); pk[7] = (short)f2bf(fr[2 * i + 1].w);
                int c = (q * 2 + i) ^ (crow & 7);    // bf16 chunk swizzle
                *(short8v*)(eb + crow * 64 + c * 8) = pk;
            }
        }
        __syncthreads();

        // ---- K-pass for this half: kidx = half*2 + {0,1}; acc carries over ----
#pragma unroll
        for (int kk = 0; kk < 2; ++kk) {
            const int ko = (half * 2 + kk) * 32;
            short8v b30 = *(const short8v*)(b3p0 + ko);
            short8v b31 = *(const short8v*)(b3p1 + ko);
            short8v b50 = *(const short8v*)(b5p0 + ko);
            short8v b51 = *(const short8v*)(b5p1 + ko);
#pragma unroll
            for (int m = 0; m < 4; ++m) {
                const int row = m * 16 + l15;
                // local bf16 chunk kk*4+kg stored at (kk*4+kg)^(row&7)
                short8v af = *(const short8v*)(eb + row * 64 + (((kk << 2) | kg) ^ (row & 7)) * 8);
                a3[m][0] = __builtin_amdgcn_mfma_f32_16x16x32_bf16(af, b30, a3[m][0], 0, 0, 0);
                a3[m][1] = __builtin_amdgcn_mfma_f32_16x16x32_bf16(af, b31, a3[m][1], 0, 0, 0);
                a5[m][0] = __builtin_amdgcn_mfma_f32_16x16x32_bf16(af, b50, a5[m][0], 0, 0, 0);
                a5[m][1] = __builtin_amdgcn_mfma_f32_16x16x32_bf16(af, b51, a5[m][1], 0, 0, 0);
            }
        }
        __syncthreads();   // all eb reads done before next half's DMA overwrites
    }

    const int nseg = __builtin_amdgcn_readfirstlane(s_nseg);

    // ---- epilogue: ex = exp(u*(v+x3)*inv) in place over a3; a5 *= ex ----
#pragma unroll
    for (int m = 0; m < 4; ++m) {
#pragma unroll
        for (int r = 0; r < 4; ++r) {
            int le = m * 16 + kg * 4 + r;
            int d  = s_dst[le];
            int sv = s_src[le];
            unsigned upk = *(const unsigned*)&uvkb[(size_t)sv * 384 + cb];
            unsigned vpk = *(const unsigned*)&uvkb[(size_t)d * 384 + 128 + cb];
            float u0 = bf2f((unsigned short)(upk & 0xffffu));
            float u1 = bf2f((unsigned short)(upk >> 16));
            float v0 = bf2f((unsigned short)(vpk & 0xffffu));
            float v1 = bf2f((unsigned short)(vpk >> 16));
            float at0 = u0 * (v0 + a3[m][0][r]) * inv;
            float at1 = u1 * (v1 + a3[m][1][r]) * inv;
            float ex0 = __expf(fminf(at0, 80.f));
            float ex1 = __expf(fminf(at1, 80.f));
            a3[m][0][r] = ex0;
            a3[m][1][r] = ex1;
            a5[m][0][r] = ex0 * a5[m][0][r];
            a5[m][1][r] = ex1 * a5[m][1][r];
        }
    }

    // ---- combined segmented reduce -> dpart, apart ----
    for (int sg = 0; sg < nseg; ++sg) {
        const int b  = __builtin_amdgcn_readfirstlane(s_sb[sg]);
        const int e2 = __builtin_amdgcn_readfirstlane(s_se[sg]);
        const int pi = __builtin_amdgcn_readfirstlane(s_pi[sg]);
        float d0 = 0.f, d1 = 0.f, g0 = 0.f, g1 = 0.f;
#pragma unroll
        for (int m = 0; m < 4; ++m) {
            if (b < m * 16 + 16 && e2 > m * 16) {   // scalar branch: skip m-block
#pragma unroll
                for (int r = 0; r < 4; ++r) {
                    int slot = m * 16 + kg * 4 + r;
                    bool in = (slot >= b) && (slot < e2);
                    d0 += in ? a3[m][0][r] : 0.f;
                    d1 += in ? a3[m][1][r] : 0.f;
                    g0 += in ? a5[m][0][r] : 0.f;
                    g1 += in ? a5[m][1][r] : 0.f;
                }
            }
        }
        d0 += __shfl_xor(d0, 16); d0 += __shfl_xor(d0, 32);
        d1 += __shfl_xor(d1, 16); d1 += __shfl_xor(d1, 32);
        g0 += __shfl_xor(g0, 16); g0 += __shfl_xor(g0, 32);
        g1 += __shfl_xor(g1, 16); g1 += __shfl_xor(g1, 32);
        if (kg == 0) {
            *(float2*)&dpart[(size_t)pi * 128 + cb] = make_float2(d0, d1);
            *(float2*)&apart[(size_t)pi * 128 + cb] = make_float2(g0, g1);
        }
    }
}

// ---------- node finalize: sum pieces, h1 = LN(hw6 + k + agg/denom) ----------
__global__ __launch_bounds__(256) void node_finalize(
    const float* __restrict__ hw6f, const unsigned short* __restrict__ uvkb,
    const float* __restrict__ dpart, const float* __restrict__ apart,
    const int* __restrict__ ppos,
    const float* __restrict__ gamma, const float* __restrict__ beta,
    float* __restrict__ h1, unsigned short* __restrict__ h1b)
{
    int n = blockIdx.x * 4 + (threadIdx.x >> 6);
    int lane = threadIdx.x & 63;
    int p0 = ppos[n], p1 = ppos[n + 1];
    float de0 = 0.f, de1 = 0.f, g0 = 0.f, g1 = 0.f;
    for (int j = p0; j < p1; ++j) {
        float2 dv = *(const float2*)&dpart[(size_t)j * 128 + lane * 2];
        float2 av = *(const float2*)&apart[(size_t)j * 128 + lane * 2];
        de0 += dv.x; de1 += dv.y;
        g0  += av.x; g1  += av.y;
    }
    unsigned kpk = *(const unsigned*)&uvkb[(size_t)n * 384 + 256 + lane * 2];
    float k0 = bf2f((unsigned short)(kpk & 0xffffu));
    float k1 = bf2f((unsigned short)(kpk >> 16));
    float2 hw = *(const float2*)&hw6f[(size_t)n * 128 + lane * 2];
    float x0 = hw.x + (de0 > 0.f ? k0 + g0 / de0 : 0.f);
    float x1 = hw.y + (de1 > 0.f ? k1 + g1 / de1 : 0.f);
    float s = x0 + x1;
#pragma unroll
    for (int off = 1; off < 64; off <<= 1) s += __shfl_xor(s, off);
    float mu = s * (1.f / 128.f);
    float d0 = x0 - mu, d1 = x1 - mu;
    float ss = d0 * d0 + d1 * d1;
#pragma unroll
    for (int off = 1; off < 64; off <<= 1) ss += __shfl_xor(ss, off);
    float rs = rsqrtf(ss * (1.f / 128.f) + 1e-5f);
    float2 g = *(const float2*)&gamma[lane * 2];
    float2 b = *(const float2*)&beta[lane * 2];
    float o0 = d0 * rs * g.x + b.x;
    float o1 = d1 * rs * g.y + b.y;
    size_t base = (size_t)n * 128 + lane * 2;
    *(float2*)&h1[base] = make_float2(o0, o1);
    *(unsigned*)&h1b[base] = pack2(o0, o1);
}

// ---------- fused MLP tail: out = LN(relu(h1@mw1)@mw2 + h1) ----------
__global__ __launch_bounds__(256, 4) void mlp_tail(
    const unsigned short* __restrict__ A,      // h1b bf16 [N][128]
    const float* __restrict__ res,             // h1 f32 [N][128]
    const unsigned short* __restrict__ mw1t, const unsigned short* __restrict__ mw2t,
    const float* __restrict__ gamma, const float* __restrict__ beta,
    float* __restrict__ out)
{
    __shared__ __align__(16) unsigned short hid[64 * 264]; // 33792 B

    const int t = threadIdx.x;
    const int lane = t & 63, wv = t >> 6;
    const int l15 = lane & 15, kg = lane >> 4;
    const int m0 = blockIdx.x * 64;
    const int M = N_NODES;

    // ---- phase A: hidden = relu(h1b @ mw1t) -> hid LDS (bf16) ----
    {
        int arow = m0 + wv * 16 + l15;
        int arow_c = arow < M ? arow : M - 1;
        const unsigned short* ap = A + (size_t)arow_c * 128 + kg * 8;
        f32x4 acc[16];
#pragma unroll
        for (int nt = 0; nt < 16; ++nt) acc[nt] = (f32x4){0.f, 0.f, 0.f, 0.f};
#pragma unroll
        for (int kidx = 0; kidx < 4; ++kidx) {
            const int ko = kidx * 32;
            short8v af = *(const short8v*)(ap + ko);
#pragma unroll
            for (int nt = 0; nt < 16; ++nt) {
                short8v bf = *(const short8v*)(mw1t + (size_t)(nt * 16 + l15) * 128 + ko + kg * 8);
                acc[nt] = __builtin_amdgcn_mfma_f32_16x16x32_bf16(af, bf, acc[nt], 0, 0, 0);
            }
        }
#pragma unroll
        for (int nt = 0; nt < 16; ++nt) {
#pragma unroll
            for (int r = 0; r < 4; ++r) {
                int row = wv * 16 + kg * 4 + r;
                int col = nt * 16 + l15;
                hid[row * 264 + col] = f2bf(fmaxf(acc[nt][r], 0.f));
            }
        }
    }
    __syncthreads();

    // ---- phase B: out = LN(hid @ mw2t + h1) ----
    {
        const int lrow = wv * 16 + l15;
        f32x4 acc[8];
#pragma unroll
        for (int nt = 0; nt < 8; ++nt) acc[nt] = (f32x4){0.f, 0.f, 0.f, 0.f};
#pragma unroll
        for (int kidx = 0; kidx < 8; ++kidx) {
            const int ko = kidx * 32;
            short8v af = *(const short8v*)&hid[lrow * 264 + ko + kg * 8];
#pragma unroll
            for (int nt = 0; nt < 8; ++nt) {
                short8v bf = *(const short8v*)(mw2t + (size_t)(nt * 16 + l15) * 256 + ko + kg * 8);
                acc[nt] = __builtin_amdgcn_mfma_f32_16x16x32_bf16(af, bf, acc[nt], 0, 0, 0);
            }
        }
        float gv[8], bv[8];
#pragma unroll
        for (int nt = 0; nt < 8; ++nt) {
            gv[nt] = gamma[nt * 16 + l15];
            bv[nt] = beta[nt * 16 + l15];
        }
#pragma unroll
        for (int r = 0; r < 4; ++r) {
            int row = m0 + wv * 16 + kg * 4 + r;
            int rc = row < M ? row : M - 1;
            float x[8];
            float s = 0.f;
#pragma unroll
            for (int nt = 0; nt < 8; ++nt) {
                x[nt] = acc[nt][r] + res[(size_t)rc * 128 + nt * 16 + l15];
                s += x[nt];
            }
#pragma unroll
            for (int off = 1; off < 16; off <<= 1) s += __shfl_xor(s, off);
            float mu = s * (1.f / 128.f);
            float ss = 0.f;
#pragma unroll
            for (int nt = 0; nt < 8; ++nt) {
                float d = x[nt] - mu;
                ss += d * d;
            }
#pragma unroll
            for (int off = 1; off < 16; off <<= 1) ss += __shfl_xor(ss, off);
            float rsv = rsqrtf(ss * (1.f / 128.f) + 1e-5f);
            if (row < M) {
#pragma unroll
                for (int nt = 0; nt < 8; ++nt)
                    out[(size_t)row * 128 + nt * 16 + l15] =
                        (x[nt] - mu) * rsv * gv[nt] + bv[nt];
            }
        }
    }
}

extern "C" void kernel_launch(void* const* d_in, const int* in_sizes, int n_in,
                              void* d_out, int out_size, void* d_ws, size_t ws_size,
                              hipStream_t stream)
{
    const float* h    = (const float*)d_in[0];
    const float* e_ij = (const float*)d_in[1];
    const float* W1   = (const float*)d_in[2];
    const float* W2   = (const float*)d_in[3];
    const float* W3   = (const float*)d_in[4];
    const float* W4   = (const float*)d_in[5];
    const float* W5   = (const float*)d_in[6];
    const float* W6   = (const float*)d_in[7];
    const float* ln_g = (const float*)d_in[8];
    const float* ln_b = (const float*)d_in[9];
    const float* mw1  = (const float*)d_in[10];
    const float* mw2  = (const float*)d_in[11];
    const int*   src  = (const int*)d_in[12];
    const int*   dst  = (const int*)d_in[13];
    float* out = (float*)d_out;

    float* ws = (float*)d_ws;
    // layout (float offsets); P_max = 112640 pieces (N + E/64 rounded up)
    float* hw6f  = ws;                                 // [100k][128]
    float* h1    = ws + 12800000;                      // [100k][128]
    float* dpart = ws + 25600000;                      // [112640][128] = 14,417,920
    float* apart = ws + 40100000;                      // [112640][128]
    unsigned short* uvkb  = (unsigned short*)(ws + 54600000);     // [100k][384]
    unsigned short* h1b   = (unsigned short*)(ws + 73800000);     // [100k][128]
    unsigned short* w3t   = (unsigned short*)(ws + 93000000);     // [128][128]
    unsigned short* w5t   = w3t + 16384;
    unsigned short* wcatt = w5t + 16384;               // [512][128]
    unsigned short* mw1t  = wcatt + 65536;             // [256][128]
    unsigned short* mw2t  = mw1t + 32768;              // [128][256]
    int* ibase    = (int*)(ws + 93100000);
    int* counts   = ibase;                             // [N]
    int* offsets  = ibase + 100000;                    // [N+1]
    int* cursor   = ibase + 200001;                    // [N]
    int* npieces  = ibase + 300001;                    // [N]
    int* ppos     = ibase + 400001;                    // [N+1]
    int* partials = ibase + 500102;                    // [128]
    int* edge_ord = ibase + 500230;                    // [E]
    int* src_ord  = edge_ord + N_EDGES;                // [E]
    int* dst_ord  = src_ord + N_EDGES;                 // [E]

    dim3 blk(256);
    hipMemsetAsync(counts, 0, N_NODES * sizeof(int), stream);

    hist_dst<<<N_EDGES / 256, blk, 0, stream>>>(dst, counts);
    scan_p1<<<98, blk, 0, stream>>>(counts, partials, N_NODES);
    scan_p2<<<1, 64, 0, stream>>>(partials, 98, offsets + N_NODES);
    scan_p3<<<98, blk, 0, stream>>>(counts, offsets, cursor, partials, N_NODES);
    scatter_edges<<<N_EDGES / 256, blk, 0, stream>>>(dst, src, cursor,
                                                     edge_ord, src_ord, dst_ord);
    calc_npieces<<<391, blk, 0, stream>>>(offsets, npieces);
    scan_p1<<<98, blk, 0, stream>>>(npieces, partials, N_NODES);
    scan_p2<<<1, 64, 0, stream>>>(partials, 98, ppos + N_NODES);
    scan_p3<<<98, blk, 0, stream>>>(npieces, ppos, (int*)nullptr, partials, N_NODES);

    prep_weights<<<576, blk, 0, stream>>>(W1, W2, W3, W4, W5, W6, mw1, mw2,
                                          w3t, w5t, wcatt, mw1t, mw2t);

    // u|v|k (bf16) and hw6 (f32) = h @ [W1|W2|W4|W6]
    gemm_node<<<dim3(1563, 4), blk, 0, stream>>>(h, wcatt, uvkb, hw6f);

    edge_agg<<<N_EDGES / 64, blk, 0, stream>>>(e_ij, w3t, w5t, uvkb,
                                               edge_ord, src_ord, dst_ord,
                                               offsets, ppos, dpart, apart);

    node_finalize<<<N_NODES / 4, blk, 0, stream>>>(hw6f, uvkb, dpart, apart, ppos,
                                                   ln_g, ln_b, h1, h1b);

    // fused MLP1 + MLP2 + LN (hidden in LDS; no hiddenb round-trip)
    mlp_tail<<<1563, blk, 0, stream>>>(h1b, h1, mw1t, mw2t, ln_g, ln_b, out);
}

// Round 12
// 612.543 us; speedup vs baseline: 2.4590x; 2.4590x over previous
//
#include <hip/hip_runtime.h>
#include <hip/hip_bf16.h>

#define N_NODES 100000
#define N_EDGES 800000

typedef __attribute__((ext_vector_type(8))) short short8v;   // 8 bf16 = 4 VGPRs
typedef __attribute__((ext_vector_type(4))) float f32x4;

__device__ __forceinline__ unsigned short f2bf(float f) {
    __hip_bfloat16 b = __float2bfloat16(f);
    return *(unsigned short*)&b;
}
__device__ __forceinline__ float bf2f(unsigned short u) {
    return __uint_as_float((unsigned)u << 16);
}
__device__ __forceinline__ unsigned pack2(float lo, float hi) {
    return (unsigned)f2bf(lo) | ((unsigned)f2bf(hi) << 16);
}

// async 16B global->LDS DMA (gfx950). LDS dest: wave-uniform base + lane*16.
__device__ __forceinline__ void gload_lds16(const void* g, void* l) {
    __builtin_amdgcn_global_load_lds(
        (const __attribute__((address_space(1))) unsigned int*)g,
        (__attribute__((address_space(3))) unsigned int*)l,
        16, 0, 0);
}

// bijective XCD-chunked block swizzle (m204).
__device__ __forceinline__ int xcd_swizzle(int orig, int q, int r) {
    int xcd = orig & 7, loc = orig >> 3;
    return (xcd < r ? xcd * (q + 1) : r * (q + 1) + (xcd - r) * q) + loc;
}

// ---------- CSR build ----------
__global__ __launch_bounds__(256) void hist_dst(
    const int* __restrict__ dst, int* __restrict__ counts)
{
    int e = blockIdx.x * 256 + threadIdx.x;
    if (e < N_EDGES) atomicAdd(&counts[dst[e]], 1);
}

__global__ __launch_bounds__(256) void scan_p1(
    const int* __restrict__ in, int* __restrict__ partials, int n)
{
    __shared__ int ws[4];
    int t = threadIdx.x, lane = t & 63, wv = t >> 6;
    int base = blockIdx.x * 1024;
    int s = 0;
#pragma unroll
    for (int i = 0; i < 4; ++i) {
        int idx = base + i * 256 + t;
        s += (idx < n) ? in[idx] : 0;
    }
#pragma unroll
    for (int off = 1; off < 64; off <<= 1) s += __shfl_xor(s, off);
    if (lane == 0) ws[wv] = s;
    __syncthreads();
    if (t == 0) partials[blockIdx.x] = ws[0] + ws[1] + ws[2] + ws[3];
}

__global__ __launch_bounds__(64) void scan_p2(
    int* __restrict__ partials, int nb, int* __restrict__ total_out)
{
    int lane = threadIdx.x;
    int carry = 0;
    for (int base = 0; base < nb; base += 64) {
        int idx = base + lane;
        int v = (idx < nb) ? partials[idx] : 0;
        int s = v;
#pragma unroll
        for (int off = 1; off < 64; off <<= 1) {
            int w = __shfl_up(s, off);
            if (lane >= off) s += w;
        }
        if (idx < nb) partials[idx] = s - v + carry;
        carry += __shfl(s, 63);
    }
    if (lane == 0) *total_out = carry;
}

__global__ __launch_bounds__(256) void scan_p3(
    const int* __restrict__ in, int* __restrict__ out, int* __restrict__ cursor,
    const int* __restrict__ partials, int n)
{
    __shared__ int ws[4];
    __shared__ int wpre[4];
    __shared__ int s_tot;
    int t = threadIdx.x, lane = t & 63, wv = t >> 6;
    int base = blockIdx.x * 1024;
    int carry = partials[blockIdx.x];
    for (int sub = 0; sub < 4; ++sub) {
        int idx = base + sub * 256 + t;
        int v = (idx < n) ? in[idx] : 0;
        int s = v;
#pragma unroll
        for (int off = 1; off < 64; off <<= 1) {
            int w = __shfl_up(s, off);
            if (lane >= off) s += w;
        }
        if (lane == 63) ws[wv] = s;
        __syncthreads();
        if (t == 0) {
            int a = 0;
#pragma unroll
            for (int i = 0; i < 4; ++i) { wpre[i] = a; a += ws[i]; }
            s_tot = a;
        }
        __syncthreads();
        int excl = s - v + wpre[wv] + carry;
        if (idx < n) { out[idx] = excl; if (cursor) cursor[idx] = excl; }
        carry += s_tot;
        __syncthreads();
    }
}

__global__ __launch_bounds__(256) void scatter_edges(
    const int* __restrict__ dst, const int* __restrict__ src,
    int* __restrict__ cursor,
    int* __restrict__ edge_ord, int* __restrict__ src_ord,
    int* __restrict__ dst_ord)
{
    int e = blockIdx.x * 256 + threadIdx.x;
    if (e < N_EDGES) {
        int d = dst[e];
        int pos = atomicAdd(&cursor[d], 1);
        edge_ord[pos] = e;
        src_ord[pos] = src[e];
        dst_ord[pos] = d;
    }
}

// npieces[n] = number of 64-slot blocks node n's slot range touches
__global__ __launch_bounds__(256) void calc_npieces(
    const int* __restrict__ offsets, int* __restrict__ npieces)
{
    int n = blockIdx.x * 256 + threadIdx.x;
    if (n < N_NODES) {
        int b = offsets[n], e = offsets[n + 1];
        npieces[n] = (e > b) ? (((e - 1) >> 6) - (b >> 6) + 1) : 0;
    }
}

// ---------- fused weight prep: w3t,w5t | wcatt | mw1t,mw2t ----------
__global__ __launch_bounds__(256) void prep_weights(
    const float* __restrict__ W1, const float* __restrict__ W2,
    const float* __restrict__ W3, const float* __restrict__ W4,
    const float* __restrict__ W5, const float* __restrict__ W6,
    const float* __restrict__ mw1, const float* __restrict__ mw2,
    unsigned short* __restrict__ w3t, unsigned short* __restrict__ w5t,
    unsigned short* __restrict__ wcatt,
    unsigned short* __restrict__ mw1t, unsigned short* __restrict__ mw2t)
{
    int bid = blockIdx.x;
    if (bid < 64) {
        int t = bid * 256 + threadIdx.x;          // 0..16383
        int r = t >> 7, c = t & 127;
        w3t[c * 128 + r] = f2bf(W3[t]);
        w5t[c * 128 + r] = f2bf(W5[t]);
    } else if (bid < 320) {
        int t = (bid - 64) * 256 + threadIdx.x;   // 0..65535
        int n = t >> 7, k = t & 127;
        const float* Wm = (n < 128) ? W1 : (n < 256) ? W2 : (n < 384) ? W4 : W6;
        wcatt[t] = f2bf(Wm[k * 128 + (n & 127)]);
    } else {
        int t = (bid - 320) * 256 + threadIdx.x;  // 0..65535
        if (t < 32768) {
            int n = t >> 7, k = t & 127;
            mw1t[t] = f2bf(mw1[k * 256 + n]);
        } else {
            int s = t - 32768;
            int n = s >> 8, k = s & 255;
            mw2t[s] = f2bf(mw2[k * 128 + n]);
        }
    }
}

// ---------- node GEMM: [u|v|k] bf16 + hw6 f32 = h(f32) @ [W1|W2|W4|W6] ----------
__global__ __launch_bounds__(256) void gemm_node(
    const float* __restrict__ A, const unsigned short* __restrict__ Bt,
    unsigned short* __restrict__ uvkb, float* __restrict__ hw6f)
{
    const int t = threadIdx.x;
    const int lane = t & 63, wv = t >> 6;
    const int l15 = lane & 15, kg = lane >> 4;
    const int m0 = blockIdx.x * 64;
    const int n0 = blockIdx.y * 128;
    const int M = N_NODES, K = 128;

    int arow = m0 + wv * 16 + l15;
    int arow_c = arow < M ? arow : M - 1;
    const float* ap = A + (size_t)arow_c * K + kg * 8;

    f32x4 acc[8];
#pragma unroll
    for (int nt = 0; nt < 8; ++nt) acc[nt] = (f32x4){0.f, 0.f, 0.f, 0.f};

    for (int ko = 0; ko < K; ko += 32) {
        float4 f0 = *(const float4*)(ap + ko);
        float4 f1 = *(const float4*)(ap + ko + 4);
        short8v af;
        af[0] = (short)f2bf(f0.x); af[1] = (short)f2bf(f0.y);
        af[2] = (short)f2bf(f0.z); af[3] = (short)f2bf(f0.w);
        af[4] = (short)f2bf(f1.x); af[5] = (short)f2bf(f1.y);
        af[6] = (short)f2bf(f1.z); af[7] = (short)f2bf(f1.w);
#pragma unroll
        for (int nt = 0; nt < 8; ++nt) {
            short8v bf = *(const short8v*)(Bt + (size_t)(n0 + nt * 16 + l15) * K + ko + kg * 8);
            acc[nt] = __builtin_amdgcn_mfma_f32_16x16x32_bf16(af, bf, acc[nt], 0, 0, 0);
        }
    }
#pragma unroll
    for (int nt = 0; nt < 8; ++nt) {
#pragma unroll
        for (int r = 0; r < 4; ++r) {
            int row = m0 + wv * 16 + kg * 4 + r;
            if (row < M) {
                int col = n0 + nt * 16 + l15;
                float vfl = acc[nt][r];
                if (n0 < 384) uvkb[(size_t)row * 384 + col] = f2bf(vfl);
                else          hw6f[(size_t)row * 128 + col - 384] = vfl;
            }
        }
    }
}

// ---------- fused edge pass + in-register segmented aggregation ----------
// v25 = exact revert to the round-10 champion edge_agg (v23): 64-edge
// one-shot blocks, async-DMA f32 stage, shared in-place f32->bf16
// conversion, fused W3/W5 K-pass, 4 blocks/CU, XCD-chunked swizzle.
// STRUCTURAL PLATEAU (~237us): acc = 64 f32/lane forces residency <= 4
// blocks/CU (round-11: (256,8) cap -> total spill, 4.1GB traffic); smaller
// tiles amplify traffic (round 7); pipelining/VALU cuts neutral (r4/r6).
__global__ __launch_bounds__(256, 4) void edge_agg(
    const float* __restrict__ e_ij,
    const unsigned short* __restrict__ w3t, const unsigned short* __restrict__ w5t,
    const unsigned short* __restrict__ uvkb,
    const int* __restrict__ edge_ord, const int* __restrict__ src_ord,
    const int* __restrict__ dst_ord,
    const int* __restrict__ offsets, const int* __restrict__ ppos,
    float* __restrict__ dpart, float* __restrict__ apart)
{
    __shared__ __align__(16) float e_s[64 * 128];   // 32 KB f32; first 16 KB re-used as bf16 tile
    __shared__ int s_eid[64], s_src[64], s_dst[64];
    __shared__ int s_sb[64], s_se[64], s_pi[64];
    __shared__ int s_nseg;

    const int t  = threadIdx.x;
    const int lane = t & 63, wv = t >> 6;
    const int l15 = lane & 15, kg = lane >> 4;
    const int cb = wv * 32 + 2 * l15;              // this lane's col pair
    const float inv = 0.17677669529663687f;        // 1/sqrt(32)

    const int nwg = N_EDGES / 64;                  // 12500
    const int bswz = xcd_swizzle((int)blockIdx.x, nwg >> 3, nwg & 7);
    const int e0 = bswz * 64;

    // ---- meta: wave 0 ballots segments ----
    if (t < 64) {
        s_eid[t] = edge_ord[e0 + t];
        s_src[t] = src_ord[e0 + t];
        int d = dst_ord[e0 + t];
        s_dst[t] = d;
        int dprev = __shfl_up(d, 1);
        bool bnd = (t == 0) || (d != dprev);
        unsigned long long mask = __ballot(bnd);
        int sid = __popcll(mask & ((1ull << t) - 1ull));
        if (bnd) {
            s_sb[sid] = t;
            s_pi[sid] = ppos[d] + bswz - (offsets[d] >> 6);
            if (t > 0) s_se[sid - 1] = t;
        }
        if (t == 63) {
            int ns = __popcll(mask);
            s_se[ns - 1] = 64;
            s_nseg = ns;
        }
    }
    __syncthreads();

    // ---- async DMA stage: 2048 chunks of 16B; thread t covers chunk i*256+t.
    // LDS f32 chunk (row, j) receives global chunk j^(row&7) of row eid[row].
#pragma unroll
    for (int i = 0; i < 8; ++i) {
        int c = i * 256 + t;
        int row = c >> 5, j = c & 31;
        int js = j ^ (row & 7);
        const float* g = e_ij + (size_t)s_eid[row] * 128 + js * 4;
        void* l = (void*)((char*)(&e_s[0]) + (size_t)i * 4096 + (size_t)wv * 1024);
        gload_lds16(g, l);
    }
    __syncthreads();   // drain: f32 tile staged

    // ---- shared conversion pass: f32 tile -> bf16 tile (in place, 1st half).
    unsigned short* eb = (unsigned short*)&e_s[0];  // bf16 [64][128], chunk c at c^(row&15)
    {
        const int crow = t >> 2, q = t & 3;
        float4 fr[8];
#pragma unroll
        for (int i = 0; i < 8; ++i) {
            int j = (q * 8 + i) ^ (crow & 7);      // stored (swizzled) f32 chunk pos
            fr[i] = *(const float4*)(&e_s[crow * 128 + j * 4]);
        }
        __syncthreads();   // ALL f32 reads complete before any bf16 write clobbers
#pragma unroll
        for (int i = 0; i < 4; ++i) {
            short8v pk;
            pk[0] = (short)f2bf(fr[2 * i].x);     pk[1] = (short)f2bf(fr[2 * i].y);
            pk[2] = (short)f2bf(fr[2 * i].z);     pk[3] = (short)f2bf(fr[2 * i].w);
            pk[4] = (short)f2bf(fr[2 * i + 1].x); pk[5] = (short)f2bf(fr[2 * i + 1].y);
            pk[6] = (short)f2bf(fr[2 * i + 1].z); pk[7] = (short)f2bf(fr[2 * i + 1].w);
            int c = (q * 4 + i) ^ (crow & 15);     // bf16 chunk swizzle
            *(short8v*)(eb + crow * 128 + c * 8) = pk;
        }
    }
    __syncthreads();

    const int nseg = __builtin_amdgcn_readfirstlane(s_nseg);

    // ---- fused K-pass: a3 = e@W3 cols, a5 = e@W5 cols; A frags direct bf16 ----
    f32x4 a3[4][2], a5[4][2];
#pragma unroll
    for (int m = 0; m < 4; ++m) {
        a3[m][0] = (f32x4){0.f, 0.f, 0.f, 0.f};
        a3[m][1] = (f32x4){0.f, 0.f, 0.f, 0.f};
        a5[m][0] = (f32x4){0.f, 0.f, 0.f, 0.f};
        a5[m][1] = (f32x4){0.f, 0.f, 0.f, 0.f};
    }
    {
        const unsigned short* b3p0 = w3t + (size_t)(cb + 0) * 128 + kg * 8;
        const unsigned short* b3p1 = w3t + (size_t)(cb + 1) * 128 + kg * 8;
        const unsigned short* b5p0 = w5t + (size_t)(cb + 0) * 128 + kg * 8;
        const unsigned short* b5p1 = w5t + (size_t)(cb + 1) * 128 + kg * 8;
#pragma unroll
        for (int kidx = 0; kidx < 4; ++kidx) {
            const int ko = kidx * 32;
            short8v b30 = *(const short8v*)(b3p0 + ko);
            short8v b31 = *(const short8v*)(b3p1 + ko);
            short8v b50 = *(const short8v*)(b5p0 + ko);
            short8v b51 = *(const short8v*)(b5p1 + ko);
#pragma unroll
            for (int m = 0; m < 4; ++m) {
                const int row = m * 16 + l15;
                short8v af = *(const short8v*)(eb + row * 128 + (((kidx << 2) | kg) ^ l15) * 8);
                a3[m][0] = __builtin_amdgcn_mfma_f32_16x16x32_bf16(af, b30, a3[m][0], 0, 0, 0);
                a3[m][1] = __builtin_amdgcn_mfma_f32_16x16x32_bf16(af, b31, a3[m][1], 0, 0, 0);
                a5[m][0] = __builtin_amdgcn_mfma_f32_16x16x32_bf16(af, b50, a5[m][0], 0, 0, 0);
                a5[m][1] = __builtin_amdgcn_mfma_f32_16x16x32_bf16(af, b51, a5[m][1], 0, 0, 0);
            }
        }
    }

    // ---- epilogue: ex = exp(u*(v+x3)*inv) in place over a3; a5 *= ex ----
#pragma unroll
    for (int m = 0; m < 4; ++m) {
#pragma unroll
        for (int r = 0; r < 4; ++r) {
            int le = m * 16 + kg * 4 + r;
            int d  = s_dst[le];
            int sv = s_src[le];
            unsigned upk = *(const unsigned*)&uvkb[(size_t)sv * 384 + cb];
            unsigned vpk = *(const unsigned*)&uvkb[(size_t)d * 384 + 128 + cb];
            float u0 = bf2f((unsigned short)(upk & 0xffffu));
            float u1 = bf2f((unsigned short)(upk >> 16));
            float v0 = bf2f((unsigned short)(vpk & 0xffffu));
            float v1 = bf2f((unsigned short)(vpk >> 16));
            float at0 = u0 * (v0 + a3[m][0][r]) * inv;
            float at1 = u1 * (v1 + a3[m][1][r]) * inv;
            float ex0 = __expf(fminf(at0, 80.f));
            float ex1 = __expf(fminf(at1, 80.f));
            a3[m][0][r] = ex0;
            a3[m][1][r] = ex1;
            a5[m][0][r] = ex0 * a5[m][0][r];
            a5[m][1][r] = ex1 * a5[m][1][r];
        }
    }

    // ---- combined segmented reduce -> dpart, apart ----
    for (int sg = 0; sg < nseg; ++sg) {
        const int b  = __builtin_amdgcn_readfirstlane(s_sb[sg]);
        const int e2 = __builtin_amdgcn_readfirstlane(s_se[sg]);
        const int pi = __builtin_amdgcn_readfirstlane(s_pi[sg]);
        float d0 = 0.f, d1 = 0.f, g0 = 0.f, g1 = 0.f;
#pragma unroll
        for (int m = 0; m < 4; ++m) {
            if (b < m * 16 + 16 && e2 > m * 16) {   // scalar branch: skip m-block
#pragma unroll
                for (int r = 0; r < 4; ++r) {
                    int slot = m * 16 + kg * 4 + r;
                    bool in = (slot >= b) && (slot < e2);
                    d0 += in ? a3[m][0][r] : 0.f;
                    d1 += in ? a3[m][1][r] : 0.f;
                    g0 += in ? a5[m][0][r] : 0.f;
                    g1 += in ? a5[m][1][r] : 0.f;
                }
            }
        }
        d0 += __shfl_xor(d0, 16); d0 += __shfl_xor(d0, 32);
        d1 += __shfl_xor(d1, 16); d1 += __shfl_xor(d1, 32);
        g0 += __shfl_xor(g0, 16); g0 += __shfl_xor(g0, 32);
        g1 += __shfl_xor(g1, 16); g1 += __shfl_xor(g1, 32);
        if (kg == 0) {
            *(float2*)&dpart[(size_t)pi * 128 + cb] = make_float2(d0, d1);
            *(float2*)&apart[(size_t)pi * 128 + cb] = make_float2(g0, g1);
        }
    }
}

// ---------- node finalize: sum pieces, h1 = LN(hw6 + k + agg/denom) ----------
__global__ __launch_bounds__(256) void node_finalize(
    const float* __restrict__ hw6f, const unsigned short* __restrict__ uvkb,
    const float* __restrict__ dpart, const float* __restrict__ apart,
    const int* __restrict__ ppos,
    const float* __restrict__ gamma, const float* __restrict__ beta,
    float* __restrict__ h1, unsigned short* __restrict__ h1b)
{
    int n = blockIdx.x * 4 + (threadIdx.x >> 6);
    int lane = threadIdx.x & 63;
    int p0 = ppos[n], p1 = ppos[n + 1];
    float de0 = 0.f, de1 = 0.f, g0 = 0.f, g1 = 0.f;
    for (int j = p0; j < p1; ++j) {
        float2 dv = *(const float2*)&dpart[(size_t)j * 128 + lane * 2];
        float2 av = *(const float2*)&apart[(size_t)j * 128 + lane * 2];
        de0 += dv.x; de1 += dv.y;
        g0  += av.x; g1  += av.y;
    }
    unsigned kpk = *(const unsigned*)&uvkb[(size_t)n * 384 + 256 + lane * 2];
    float k0 = bf2f((unsigned short)(kpk & 0xffffu));
    float k1 = bf2f((unsigned short)(kpk >> 16));
    float2 hw = *(const float2*)&hw6f[(size_t)n * 128 + lane * 2];
    float x0 = hw.x + (de0 > 0.f ? k0 + g0 / de0 : 0.f);
    float x1 = hw.y + (de1 > 0.f ? k1 + g1 / de1 : 0.f);
    float s = x0 + x1;
#pragma unroll
    for (int off = 1; off < 64; off <<= 1) s += __shfl_xor(s, off);
    float mu = s * (1.f / 128.f);
    float d0 = x0 - mu, d1 = x1 - mu;
    float ss = d0 * d0 + d1 * d1;
#pragma unroll
    for (int off = 1; off < 64; off <<= 1) ss += __shfl_xor(ss, off);
    float rs = rsqrtf(ss * (1.f / 128.f) + 1e-5f);
    float2 g = *(const float2*)&gamma[lane * 2];
    float2 b = *(const float2*)&beta[lane * 2];
    float o0 = d0 * rs * g.x + b.x;
    float o1 = d1 * rs * g.y + b.y;
    size_t base = (size_t)n * 128 + lane * 2;
    *(float2*)&h1[base] = make_float2(o0, o1);
    *(unsigned*)&h1b[base] = pack2(o0, o1);
}

// ---------- fused MLP tail: out = LN(relu(h1@mw1)@mw2 + h1) ----------
__global__ __launch_bounds__(256, 4) void mlp_tail(
    const unsigned short* __restrict__ A,      // h1b bf16 [N][128]
    const float* __restrict__ res,             // h1 f32 [N][128]
    const unsigned short* __restrict__ mw1t, const unsigned short* __restrict__ mw2t,
    const float* __restrict__ gamma, const float* __restrict__ beta,
    float* __restrict__ out)
{
    __shared__ __align__(16) unsigned short hid[64 * 264]; // 33792 B

    const int t = threadIdx.x;
    const int lane = t & 63, wv = t >> 6;
    const int l15 = lane & 15, kg = lane >> 4;
    const int m0 = blockIdx.x * 64;
    const int M = N_NODES;

    // ---- phase A: hidden = relu(h1b @ mw1t) -> hid LDS (bf16) ----
    {
        int arow = m0 + wv * 16 + l15;
        int arow_c = arow < M ? arow : M - 1;
        const unsigned short* ap = A + (size_t)arow_c * 128 + kg * 8;
        f32x4 acc[16];
#pragma unroll
        for (int nt = 0; nt < 16; ++nt) acc[nt] = (f32x4){0.f, 0.f, 0.f, 0.f};
#pragma unroll
        for (int kidx = 0; kidx < 4; ++kidx) {
            const int ko = kidx * 32;
            short8v af = *(const short8v*)(ap + ko);
#pragma unroll
            for (int nt = 0; nt < 16; ++nt) {
                short8v bf = *(const short8v*)(mw1t + (size_t)(nt * 16 + l15) * 128 + ko + kg * 8);
                acc[nt] = __builtin_amdgcn_mfma_f32_16x16x32_bf16(af, bf, acc[nt], 0, 0, 0);
            }
        }
#pragma unroll
        for (int nt = 0; nt < 16; ++nt) {
#pragma unroll
            for (int r = 0; r < 4; ++r) {
                int row = wv * 16 + kg * 4 + r;
                int col = nt * 16 + l15;
                hid[row * 264 + col] = f2bf(fmaxf(acc[nt][r], 0.f));
            }
        }
    }
    __syncthreads();

    // ---- phase B: out = LN(hid @ mw2t + h1) ----
    {
        const int lrow = wv * 16 + l15;
        f32x4 acc[8];
#pragma unroll
        for (int nt = 0; nt < 8; ++nt) acc[nt] = (f32x4){0.f, 0.f, 0.f, 0.f};
#pragma unroll
        for (int kidx = 0; kidx < 8; ++kidx) {
            const int ko = kidx * 32;
            short8v af = *(const short8v*)&hid[lrow * 264 + ko + kg * 8];
#pragma unroll
            for (int nt = 0; nt < 8; ++nt) {
                short8v bf = *(const short8v*)(mw2t + (size_t)(nt * 16 + l15) * 256 + ko + kg * 8);
                acc[nt] = __builtin_amdgcn_mfma_f32_16x16x32_bf16(af, bf, acc[nt], 0, 0, 0);
            }
        }
        float gv[8], bv[8];
#pragma unroll
        for (int nt = 0; nt < 8; ++nt) {
            gv[nt] = gamma[nt * 16 + l15];
            bv[nt] = beta[nt * 16 + l15];
        }
#pragma unroll
        for (int r = 0; r < 4; ++r) {
            int row = m0 + wv * 16 + kg * 4 + r;
            int rc = row < M ? row : M - 1;
            float x[8];
            float s = 0.f;
#pragma unroll
            for (int nt = 0; nt < 8; ++nt) {
                x[nt] = acc[nt][r] + res[(size_t)rc * 128 + nt * 16 + l15];
                s += x[nt];
            }
#pragma unroll
            for (int off = 1; off < 16; off <<= 1) s += __shfl_xor(s, off);
            float mu = s * (1.f / 128.f);
            float ss = 0.f;
#pragma unroll
            for (int nt = 0; nt < 8; ++nt) {
                float d = x[nt] - mu;
                ss += d * d;
            }
#pragma unroll
            for (int off = 1; off < 16; off <<= 1) ss += __shfl_xor(ss, off);
            float rsv = rsqrtf(ss * (1.f / 128.f) + 1e-5f);
            if (row < M) {
#pragma unroll
                for (int nt = 0; nt < 8; ++nt)
                    out[(size_t)row * 128 + nt * 16 + l15] =
                        (x[nt] - mu) * rsv * gv[nt] + bv[nt];
            }
        }
    }
}

extern "C" void kernel_launch(void* const* d_in, const int* in_sizes, int n_in,
                              void* d_out, int out_size, void* d_ws, size_t ws_size,
                              hipStream_t stream)
{
    const float* h    = (const float*)d_in[0];
    const float* e_ij = (const float*)d_in[1];
    const float* W1   = (const float*)d_in[2];
    const float* W2   = (const float*)d_in[3];
    const float* W3   = (const float*)d_in[4];
    const float* W4   = (const float*)d_in[5];
    const float* W5   = (const float*)d_in[6];
    const float* W6   = (const float*)d_in[7];
    const float* ln_g = (const float*)d_in[8];
    const float* ln_b = (const float*)d_in[9];
    const float* mw1  = (const float*)d_in[10];
    const float* mw2  = (const float*)d_in[11];
    const int*   src  = (const int*)d_in[12];
    const int*   dst  = (const int*)d_in[13];
    float* out = (float*)d_out;

    float* ws = (float*)d_ws;
    // layout (float offsets); P_max = 112640 pieces (N + E/64 rounded up)
    float* hw6f  = ws;                                 // [100k][128]
    float* h1    = ws + 12800000;                      // [100k][128]
    float* dpart = ws + 25600000;                      // [112640][128] = 14,417,920
    float* apart = ws + 40100000;                      // [112640][128]
    unsigned short* uvkb  = (unsigned short*)(ws + 54600000);     // [100k][384]
    unsigned short* h1b   = (unsigned short*)(ws + 73800000);     // [100k][128]
    unsigned short* w3t   = (unsigned short*)(ws + 93000000);     // [128][128]
    unsigned short* w5t   = w3t + 16384;
    unsigned short* wcatt = w5t + 16384;               // [512][128]
    unsigned short* mw1t  = wcatt + 65536;             // [256][128]
    unsigned short* mw2t  = mw1t + 32768;              // [128][256]
    int* ibase    = (int*)(ws + 93100000);
    int* counts   = ibase;                             // [N]
    int* offsets  = ibase + 100000;                    // [N+1]
    int* cursor   = ibase + 200001;                    // [N]
    int* npieces  = ibase + 300001;                    // [N]
    int* ppos     = ibase + 400001;                    // [N+1]
    int* partials = ibase + 500102;                    // [128]
    int* edge_ord = ibase + 500230;                    // [E]
    int* src_ord  = edge_ord + N_EDGES;                // [E]
    int* dst_ord  = src_ord + N_EDGES;                 // [E]

    dim3 blk(256);
    hipMemsetAsync(counts, 0, N_NODES * sizeof(int), stream);

    hist_dst<<<N_EDGES / 256, blk, 0, stream>>>(dst, counts);
    scan_p1<<<98, blk, 0, stream>>>(counts, partials, N_NODES);
    scan_p2<<<1, 64, 0, stream>>>(partials, 98, offsets + N_NODES);
    scan_p3<<<98, blk, 0, stream>>>(counts, offsets, cursor, partials, N_NODES);
    scatter_edges<<<N_EDGES / 256, blk, 0, stream>>>(dst, src, cursor,
                                                     edge_ord, src_ord, dst_ord);
    calc_npieces<<<391, blk, 0, stream>>>(offsets, npieces);
    scan_p1<<<98, blk, 0, stream>>>(npieces, partials, N_NODES);
    scan_p2<<<1, 64, 0, stream>>>(partials, 98, ppos + N_NODES);
    scan_p3<<<98, blk, 0, stream>>>(npieces, ppos, (int*)nullptr, partials, N_NODES);

    prep_weights<<<576, blk, 0, stream>>>(W1, W2, W3, W4, W5, W6, mw1, mw2,
                                          w3t, w5t, wcatt, mw1t, mw2t);

    // u|v|k (bf16) and hw6 (f32) = h @ [W1|W2|W4|W6]
    gemm_node<<<dim3(1563, 4), blk, 0, stream>>>(h, wcatt, uvkb, hw6f);

    edge_agg<<<N_EDGES / 64, blk, 0, stream>>>(e_ij, w3t, w5t, uvkb,
                                               edge_ord, src_ord, dst_ord,
                                               offsets, ppos, dpart, apart);

    node_finalize<<<N_NODES / 4, blk, 0, stream>>>(hw6f, uvkb, dpart, apart, ppos,
                                                   ln_g, ln_b, h1, h1b);

    // fused MLP1 + MLP2 + LN (hidden in LDS; no hiddenb round-trip)
    mlp_tail<<<1563, blk, 0, stream>>>(h1b, h1, mw1t, mw2t, ln_g, ln_b, out);
}

// Round 13
// 607.332 us; speedup vs baseline: 2.4801x; 1.0086x over previous
//
#include <hip/hip_runtime.h>
#include <hip/hip_bf16.h>

#define N_NODES 100000
#define N_EDGES 800000

typedef __attribute__((ext_vector_type(8))) short short8v;   // 8 bf16 = 4 VGPRs
typedef __attribute__((ext_vector_type(4))) float f32x4;

__device__ __forceinline__ unsigned short f2bf(float f) {
    __hip_bfloat16 b = __float2bfloat16(f);
    return *(unsigned short*)&b;
}
__device__ __forceinline__ float bf2f(unsigned short u) {
    return __uint_as_float((unsigned)u << 16);
}
__device__ __forceinline__ unsigned pack2(float lo, float hi) {
    return (unsigned)f2bf(lo) | ((unsigned)f2bf(hi) << 16);
}

// async 16B global->LDS DMA (gfx950). LDS dest: wave-uniform base + lane*16.
__device__ __forceinline__ void gload_lds16(const void* g, void* l) {
    __builtin_amdgcn_global_load_lds(
        (const __attribute__((address_space(1))) unsigned int*)g,
        (__attribute__((address_space(3))) unsigned int*)l,
        16, 0, 0);
}

// bijective XCD-chunked block swizzle (m204).
__device__ __forceinline__ int xcd_swizzle(int orig, int q, int r) {
    int xcd = orig & 7, loc = orig >> 3;
    return (xcd < r ? xcd * (q + 1) : r * (q + 1) + (xcd - r) * q) + loc;
}

// ---------- CSR build ----------
__global__ __launch_bounds__(256) void hist_dst(
    const int* __restrict__ dst, int* __restrict__ counts)
{
    int e = blockIdx.x * 256 + threadIdx.x;
    if (e < N_EDGES) atomicAdd(&counts[dst[e]], 1);
}

__global__ __launch_bounds__(256) void scan_p1(
    const int* __restrict__ in, int* __restrict__ partials, int n)
{
    __shared__ int ws[4];
    int t = threadIdx.x, lane = t & 63, wv = t >> 6;
    int base = blockIdx.x * 1024;
    int s = 0;
#pragma unroll
    for (int i = 0; i < 4; ++i) {
        int idx = base + i * 256 + t;
        s += (idx < n) ? in[idx] : 0;
    }
#pragma unroll
    for (int off = 1; off < 64; off <<= 1) s += __shfl_xor(s, off);
    if (lane == 0) ws[wv] = s;
    __syncthreads();
    if (t == 0) partials[blockIdx.x] = ws[0] + ws[1] + ws[2] + ws[3];
}

__global__ __launch_bounds__(64) void scan_p2(
    int* __restrict__ partials, int nb, int* __restrict__ total_out)
{
    int lane = threadIdx.x;
    int carry = 0;
    for (int base = 0; base < nb; base += 64) {
        int idx = base + lane;
        int v = (idx < nb) ? partials[idx] : 0;
        int s = v;
#pragma unroll
        for (int off = 1; off < 64; off <<= 1) {
            int w = __shfl_up(s, off);
            if (lane >= off) s += w;
        }
        if (idx < nb) partials[idx] = s - v + carry;
        carry += __shfl(s, 63);
    }
    if (lane == 0) *total_out = carry;
}

__global__ __launch_bounds__(256) void scan_p3(
    const int* __restrict__ in, int* __restrict__ out, int* __restrict__ cursor,
    const int* __restrict__ partials, int n)
{
    __shared__ int ws[4];
    __shared__ int wpre[4];
    __shared__ int s_tot;
    int t = threadIdx.x, lane = t & 63, wv = t >> 6;
    int base = blockIdx.x * 1024;
    int carry = partials[blockIdx.x];
    for (int sub = 0; sub < 4; ++sub) {
        int idx = base + sub * 256 + t;
        int v = (idx < n) ? in[idx] : 0;
        int s = v;
#pragma unroll
        for (int off = 1; off < 64; off <<= 1) {
            int w = __shfl_up(s, off);
            if (lane >= off) s += w;
        }
        if (lane == 63) ws[wv] = s;
        __syncthreads();
        if (t == 0) {
            int a = 0;
#pragma unroll
            for (int i = 0; i < 4; ++i) { wpre[i] = a; a += ws[i]; }
            s_tot = a;
        }
        __syncthreads();
        int excl = s - v + wpre[wv] + carry;
        if (idx < n) { out[idx] = excl; if (cursor) cursor[idx] = excl; }
        carry += s_tot;
        __syncthreads();
    }
}

__global__ __launch_bounds__(256) void scatter_edges(
    const int* __restrict__ dst, const int* __restrict__ src,
    int* __restrict__ cursor,
    int* __restrict__ edge_ord, int* __restrict__ src_ord,
    int* __restrict__ dst_ord)
{
    int e = blockIdx.x * 256 + threadIdx.x;
    if (e < N_EDGES) {
        int d = dst[e];
        int pos = atomicAdd(&cursor[d], 1);
        edge_ord[pos] = e;
        src_ord[pos] = src[e];
        dst_ord[pos] = d;
    }
}

// npieces[n] = number of 64-slot blocks node n's slot range touches
__global__ __launch_bounds__(256) void calc_npieces(
    const int* __restrict__ offsets, int* __restrict__ npieces)
{
    int n = blockIdx.x * 256 + threadIdx.x;
    if (n < N_NODES) {
        int b = offsets[n], e = offsets[n + 1];
        npieces[n] = (e > b) ? (((e - 1) >> 6) - (b >> 6) + 1) : 0;
    }
}

// ---------- fused weight prep: w3t,w5t | wcatt | mw1t,mw2t ----------
__global__ __launch_bounds__(256) void prep_weights(
    const float* __restrict__ W1, const float* __restrict__ W2,
    const float* __restrict__ W3, const float* __restrict__ W4,
    const float* __restrict__ W5, const float* __restrict__ W6,
    const float* __restrict__ mw1, const float* __restrict__ mw2,
    unsigned short* __restrict__ w3t, unsigned short* __restrict__ w5t,
    unsigned short* __restrict__ wcatt,
    unsigned short* __restrict__ mw1t, unsigned short* __restrict__ mw2t)
{
    int bid = blockIdx.x;
    if (bid < 64) {
        int t = bid * 256 + threadIdx.x;          // 0..16383
        int r = t >> 7, c = t & 127;
        w3t[c * 128 + r] = f2bf(W3[t]);
        w5t[c * 128 + r] = f2bf(W5[t]);
    } else if (bid < 320) {
        int t = (bid - 64) * 256 + threadIdx.x;   // 0..65535
        int n = t >> 7, k = t & 127;
        const float* Wm = (n < 128) ? W1 : (n < 256) ? W2 : (n < 384) ? W4 : W6;
        wcatt[t] = f2bf(Wm[k * 128 + (n & 127)]);
    } else {
        int t = (bid - 320) * 256 + threadIdx.x;  // 0..65535
        if (t < 32768) {
            int n = t >> 7, k = t & 127;
            mw1t[t] = f2bf(mw1[k * 256 + n]);
        } else {
            int s = t - 32768;
            int n = s >> 8, k = s & 255;
            mw2t[s] = f2bf(mw2[k * 128 + n]);
        }
    }
}

// ---------- node GEMM v2: one block = 64-row stripe, ALL 512 cols ----------
// v26: A (h rows) staged ONCE via async global_load_lds (XOR-preswizzled
// source) + shared in-place f32->bf16 conversion (edge_agg's verified
// template), then 4 sequential column-panel passes read A-fragments from
// LDS. Was grid (1563,4): each panel-block re-streamed the same A rows from
// HBM (4x re-read = 205MB vs 51MB) with v15-style scattered per-lane loads,
// and converted f32->bf16 4x. LDS 32.8KB -> 4 blocks/CU; peak live regs ~70.
__global__ __launch_bounds__(256, 4) void gemm_node(
    const float* __restrict__ A, const unsigned short* __restrict__ Bt,
    unsigned short* __restrict__ uvkb, float* __restrict__ hw6f)
{
    __shared__ __align__(16) float a_s[64 * 128];   // 32 KB f32; first 16 KB reused as bf16

    const int t = threadIdx.x;
    const int lane = t & 63, wv = t >> 6;
    const int l15 = lane & 15, kg = lane >> 4;
    const int m0 = blockIdx.x * 64;
    const int M = N_NODES;

    // ---- async DMA stage: 2048 chunks of 16B; LDS f32 chunk (row, j)
    // receives global chunk j^(row&7) of h row m0+row (clamped).
#pragma unroll
    for (int i = 0; i < 8; ++i) {
        int c = i * 256 + t;
        int row = c >> 5, j = c & 31;
        int js = j ^ (row & 7);
        int gr = m0 + row; if (gr >= M) gr = M - 1;
        const float* g = A + (size_t)gr * 128 + js * 4;
        void* l = (void*)((char*)(&a_s[0]) + (size_t)i * 4096 + (size_t)wv * 1024);
        gload_lds16(g, l);
    }
    __syncthreads();   // drain: f32 tile staged

    // ---- shared conversion pass: f32 tile -> bf16 tile (in place, 1st half)
    unsigned short* ab = (unsigned short*)&a_s[0];  // bf16 [64][128], chunk c at c^(row&15)
    {
        const int crow = t >> 2, q = t & 3;
        float4 fr[8];
#pragma unroll
        for (int i = 0; i < 8; ++i) {
            int j = (q * 8 + i) ^ (crow & 7);      // stored (swizzled) f32 chunk pos
            fr[i] = *(const float4*)(&a_s[crow * 128 + j * 4]);
        }
        __syncthreads();   // ALL f32 reads complete before bf16 writes clobber
#pragma unroll
        for (int i = 0; i < 4; ++i) {
            short8v pk;
            pk[0] = (short)f2bf(fr[2 * i].x);     pk[1] = (short)f2bf(fr[2 * i].y);
            pk[2] = (short)f2bf(fr[2 * i].z);     pk[3] = (short)f2bf(fr[2 * i].w);
            pk[4] = (short)f2bf(fr[2 * i + 1].x); pk[5] = (short)f2bf(fr[2 * i + 1].y);
            pk[6] = (short)f2bf(fr[2 * i + 1].z); pk[7] = (short)f2bf(fr[2 * i + 1].w);
            int c = (q * 4 + i) ^ (crow & 15);     // bf16 chunk swizzle
            *(short8v*)(ab + crow * 128 + c * 8) = pk;
        }
    }
    __syncthreads();

    // ---- 4 sequential column panels; A fragments from LDS (read-only) ----
    for (int panel = 0; panel < 4; ++panel) {
        const int n0 = panel * 128;
        f32x4 acc[8];
#pragma unroll
        for (int nt = 0; nt < 8; ++nt) acc[nt] = (f32x4){0.f, 0.f, 0.f, 0.f};
#pragma unroll
        for (int kidx = 0; kidx < 4; ++kidx) {
            const int ko = kidx * 32;
            const int row = wv * 16 + l15;         // row&15 = l15
            short8v af = *(const short8v*)(ab + row * 128 + (((kidx << 2) | kg) ^ l15) * 8);
#pragma unroll
            for (int nt = 0; nt < 8; ++nt) {
                short8v bf = *(const short8v*)(Bt + (size_t)(n0 + nt * 16 + l15) * 128 + ko + kg * 8);
                acc[nt] = __builtin_amdgcn_mfma_f32_16x16x32_bf16(af, bf, acc[nt], 0, 0, 0);
            }
        }
#pragma unroll
        for (int nt = 0; nt < 8; ++nt) {
#pragma unroll
            for (int r = 0; r < 4; ++r) {
                int row = m0 + wv * 16 + kg * 4 + r;
                if (row < M) {
                    int col = n0 + nt * 16 + l15;
                    float vfl = acc[nt][r];
                    if (panel < 3) uvkb[(size_t)row * 384 + col] = f2bf(vfl);
                    else           hw6f[(size_t)row * 128 + col - 384] = vfl;
                }
            }
        }
    }
}

// ---------- fused edge pass + in-register segmented aggregation ----------
// Round-10/12 champion edge_agg (structural plateau ~237us): 64-edge
// one-shot blocks, async-DMA f32 stage, shared in-place f32->bf16
// conversion, fused W3/W5 K-pass, 4 blocks/CU, XCD-chunked swizzle.
__global__ __launch_bounds__(256, 4) void edge_agg(
    const float* __restrict__ e_ij,
    const unsigned short* __restrict__ w3t, const unsigned short* __restrict__ w5t,
    const unsigned short* __restrict__ uvkb,
    const int* __restrict__ edge_ord, const int* __restrict__ src_ord,
    const int* __restrict__ dst_ord,
    const int* __restrict__ offsets, const int* __restrict__ ppos,
    float* __restrict__ dpart, float* __restrict__ apart)
{
    __shared__ __align__(16) float e_s[64 * 128];   // 32 KB f32; first 16 KB re-used as bf16 tile
    __shared__ int s_eid[64], s_src[64], s_dst[64];
    __shared__ int s_sb[64], s_se[64], s_pi[64];
    __shared__ int s_nseg;

    const int t  = threadIdx.x;
    const int lane = t & 63, wv = t >> 6;
    const int l15 = lane & 15, kg = lane >> 4;
    const int cb = wv * 32 + 2 * l15;              // this lane's col pair
    const float inv = 0.17677669529663687f;        // 1/sqrt(32)

    const int nwg = N_EDGES / 64;                  // 12500
    const int bswz = xcd_swizzle((int)blockIdx.x, nwg >> 3, nwg & 7);
    const int e0 = bswz * 64;

    // ---- meta: wave 0 ballots segments ----
    if (t < 64) {
        s_eid[t] = edge_ord[e0 + t];
        s_src[t] = src_ord[e0 + t];
        int d = dst_ord[e0 + t];
        s_dst[t] = d;
        int dprev = __shfl_up(d, 1);
        bool bnd = (t == 0) || (d != dprev);
        unsigned long long mask = __ballot(bnd);
        int sid = __popcll(mask & ((1ull << t) - 1ull));
        if (bnd) {
            s_sb[sid] = t;
            s_pi[sid] = ppos[d] + bswz - (offsets[d] >> 6);
            if (t > 0) s_se[sid - 1] = t;
        }
        if (t == 63) {
            int ns = __popcll(mask);
            s_se[ns - 1] = 64;
            s_nseg = ns;
        }
    }
    __syncthreads();

    // ---- async DMA stage: 2048 chunks of 16B; thread t covers chunk i*256+t.
    // LDS f32 chunk (row, j) receives global chunk j^(row&7) of row eid[row].
#pragma unroll
    for (int i = 0; i < 8; ++i) {
        int c = i * 256 + t;
        int row = c >> 5, j = c & 31;
        int js = j ^ (row & 7);
        const float* g = e_ij + (size_t)s_eid[row] * 128 + js * 4;
        void* l = (void*)((char*)(&e_s[0]) + (size_t)i * 4096 + (size_t)wv * 1024);
        gload_lds16(g, l);
    }
    __syncthreads();   // drain: f32 tile staged

    // ---- shared conversion pass: f32 tile -> bf16 tile (in place, 1st half).
    unsigned short* eb = (unsigned short*)&e_s[0];  // bf16 [64][128], chunk c at c^(row&15)
    {
        const int crow = t >> 2, q = t & 3;
        float4 fr[8];
#pragma unroll
        for (int i = 0; i < 8; ++i) {
            int j = (q * 8 + i) ^ (crow & 7);      // stored (swizzled) f32 chunk pos
            fr[i] = *(const float4*)(&e_s[crow * 128 + j * 4]);
        }
        __syncthreads();   // ALL f32 reads complete before any bf16 write clobbers
#pragma unroll
        for (int i = 0; i < 4; ++i) {
            short8v pk;
            pk[0] = (short)f2bf(fr[2 * i].x);     pk[1] = (short)f2bf(fr[2 * i].y);
            pk[2] = (short)f2bf(fr[2 * i].z);     pk[3] = (short)f2bf(fr[2 * i].w);
            pk[4] = (short)f2bf(fr[2 * i + 1].x); pk[5] = (short)f2bf(fr[2 * i + 1].y);
            pk[6] = (short)f2bf(fr[2 * i + 1].z); pk[7] = (short)f2bf(fr[2 * i + 1].w);
            int c = (q * 4 + i) ^ (crow & 15);     // bf16 chunk swizzle
            *(short8v*)(eb + crow * 128 + c * 8) = pk;
        }
    }
    __syncthreads();

    const int nseg = __builtin_amdgcn_readfirstlane(s_nseg);

    // ---- fused K-pass: a3 = e@W3 cols, a5 = e@W5 cols; A frags direct bf16 ----
    f32x4 a3[4][2], a5[4][2];
#pragma unroll
    for (int m = 0; m < 4; ++m) {
        a3[m][0] = (f32x4){0.f, 0.f, 0.f, 0.f};
        a3[m][1] = (f32x4){0.f, 0.f, 0.f, 0.f};
        a5[m][0] = (f32x4){0.f, 0.f, 0.f, 0.f};
        a5[m][1] = (f32x4){0.f, 0.f, 0.f, 0.f};
    }
    {
        const unsigned short* b3p0 = w3t + (size_t)(cb + 0) * 128 + kg * 8;
        const unsigned short* b3p1 = w3t + (size_t)(cb + 1) * 128 + kg * 8;
        const unsigned short* b5p0 = w5t + (size_t)(cb + 0) * 128 + kg * 8;
        const unsigned short* b5p1 = w5t + (size_t)(cb + 1) * 128 + kg * 8;
#pragma unroll
        for (int kidx = 0; kidx < 4; ++kidx) {
            const int ko = kidx * 32;
            short8v b30 = *(const short8v*)(b3p0 + ko);
            short8v b31 = *(const short8v*)(b3p1 + ko);
            short8v b50 = *(const short8v*)(b5p0 + ko);
            short8v b51 = *(const short8v*)(b5p1 + ko);
#pragma unroll
            for (int m = 0; m < 4; ++m) {
                const int row = m * 16 + l15;
                short8v af = *(const short8v*)(eb + row * 128 + (((kidx << 2) | kg) ^ l15) * 8);
                a3[m][0] = __builtin_amdgcn_mfma_f32_16x16x32_bf16(af, b30, a3[m][0], 0, 0, 0);
                a3[m][1] = __builtin_amdgcn_mfma_f32_16x16x32_bf16(af, b31, a3[m][1], 0, 0, 0);
                a5[m][0] = __builtin_amdgcn_mfma_f32_16x16x32_bf16(af, b50, a5[m][0], 0, 0, 0);
                a5[m][1] = __builtin_amdgcn_mfma_f32_16x16x32_bf16(af, b51, a5[m][1], 0, 0, 0);
            }
        }
    }

    // ---- epilogue: ex = exp(u*(v+x3)*inv) in place over a3; a5 *= ex ----
#pragma unroll
    for (int m = 0; m < 4; ++m) {
#pragma unroll
        for (int r = 0; r < 4; ++r) {
            int le = m * 16 + kg * 4 + r;
            int d  = s_dst[le];
            int sv = s_src[le];
            unsigned upk = *(const unsigned*)&uvkb[(size_t)sv * 384 + cb];
            unsigned vpk = *(const unsigned*)&uvkb[(size_t)d * 384 + 128 + cb];
            float u0 = bf2f((unsigned short)(upk & 0xffffu));
            float u1 = bf2f((unsigned short)(upk >> 16));
            float v0 = bf2f((unsigned short)(vpk & 0xffffu));
            float v1 = bf2f((unsigned short)(vpk >> 16));
            float at0 = u0 * (v0 + a3[m][0][r]) * inv;
            float at1 = u1 * (v1 + a3[m][1][r]) * inv;
            float ex0 = __expf(fminf(at0, 80.f));
            float ex1 = __expf(fminf(at1, 80.f));
            a3[m][0][r] = ex0;
            a3[m][1][r] = ex1;
            a5[m][0][r] = ex0 * a5[m][0][r];
            a5[m][1][r] = ex1 * a5[m][1][r];
        }
    }

    // ---- combined segmented reduce -> dpart, apart ----
    for (int sg = 0; sg < nseg; ++sg) {
        const int b  = __builtin_amdgcn_readfirstlane(s_sb[sg]);
        const int e2 = __builtin_amdgcn_readfirstlane(s_se[sg]);
        const int pi = __builtin_amdgcn_readfirstlane(s_pi[sg]);
        float d0 = 0.f, d1 = 0.f, g0 = 0.f, g1 = 0.f;
#pragma unroll
        for (int m = 0; m < 4; ++m) {
            if (b < m * 16 + 16 && e2 > m * 16) {   // scalar branch: skip m-block
#pragma unroll
                for (int r = 0; r < 4; ++r) {
                    int slot = m * 16 + kg * 4 + r;
                    bool in = (slot >= b) && (slot < e2);
                    d0 += in ? a3[m][0][r] : 0.f;
                    d1 += in ? a3[m][1][r] : 0.f;
                    g0 += in ? a5[m][0][r] : 0.f;
                    g1 += in ? a5[m][1][r] : 0.f;
                }
            }
        }
        d0 += __shfl_xor(d0, 16); d0 += __shfl_xor(d0, 32);
        d1 += __shfl_xor(d1, 16); d1 += __shfl_xor(d1, 32);
        g0 += __shfl_xor(g0, 16); g0 += __shfl_xor(g0, 32);
        g1 += __shfl_xor(g1, 16); g1 += __shfl_xor(g1, 32);
        if (kg == 0) {
            *(float2*)&dpart[(size_t)pi * 128 + cb] = make_float2(d0, d1);
            *(float2*)&apart[(size_t)pi * 128 + cb] = make_float2(g0, g1);
        }
    }
}

// ---------- node finalize: sum pieces, h1 = LN(hw6 + k + agg/denom) ----------
__global__ __launch_bounds__(256) void node_finalize(
    const float* __restrict__ hw6f, const unsigned short* __restrict__ uvkb,
    const float* __restrict__ dpart, const float* __restrict__ apart,
    const int* __restrict__ ppos,
    const float* __restrict__ gamma, const float* __restrict__ beta,
    float* __restrict__ h1, unsigned short* __restrict__ h1b)
{
    int n = blockIdx.x * 4 + (threadIdx.x >> 6);
    int lane = threadIdx.x & 63;
    int p0 = ppos[n], p1 = ppos[n + 1];
    float de0 = 0.f, de1 = 0.f, g0 = 0.f, g1 = 0.f;
    for (int j = p0; j < p1; ++j) {
        float2 dv = *(const float2*)&dpart[(size_t)j * 128 + lane * 2];
        float2 av = *(const float2*)&apart[(size_t)j * 128 + lane * 2];
        de0 += dv.x; de1 += dv.y;
        g0  += av.x; g1  += av.y;
    }
    unsigned kpk = *(const unsigned*)&uvkb[(size_t)n * 384 + 256 + lane * 2];
    float k0 = bf2f((unsigned short)(kpk & 0xffffu));
    float k1 = bf2f((unsigned short)(kpk >> 16));
    float2 hw = *(const float2*)&hw6f[(size_t)n * 128 + lane * 2];
    float x0 = hw.x + (de0 > 0.f ? k0 + g0 / de0 : 0.f);
    float x1 = hw.y + (de1 > 0.f ? k1 + g1 / de1 : 0.f);
    float s = x0 + x1;
#pragma unroll
    for (int off = 1; off < 64; off <<= 1) s += __shfl_xor(s, off);
    float mu = s * (1.f / 128.f);
    float d0 = x0 - mu, d1 = x1 - mu;
    float ss = d0 * d0 + d1 * d1;
#pragma unroll
    for (int off = 1; off < 64; off <<= 1) ss += __shfl_xor(ss, off);
    float rs = rsqrtf(ss * (1.f / 128.f) + 1e-5f);
    float2 g = *(const float2*)&gamma[lane * 2];
    float2 b = *(const float2*)&beta[lane * 2];
    float o0 = d0 * rs * g.x + b.x;
    float o1 = d1 * rs * g.y + b.y;
    size_t base = (size_t)n * 128 + lane * 2;
    *(float2*)&h1[base] = make_float2(o0, o1);
    *(unsigned*)&h1b[base] = pack2(o0, o1);
}

// ---------- fused MLP tail: out = LN(relu(h1@mw1)@mw2 + h1) ----------
__global__ __launch_bounds__(256, 4) void mlp_tail(
    const unsigned short* __restrict__ A,      // h1b bf16 [N][128]
    const float* __restrict__ res,             // h1 f32 [N][128]
    const unsigned short* __restrict__ mw1t, const unsigned short* __restrict__ mw2t,
    const float* __restrict__ gamma, const float* __restrict__ beta,
    float* __restrict__ out)
{
    __shared__ __align__(16) unsigned short hid[64 * 264]; // 33792 B

    const int t = threadIdx.x;
    const int lane = t & 63, wv = t >> 6;
    const int l15 = lane & 15, kg = lane >> 4;
    const int m0 = blockIdx.x * 64;
    const int M = N_NODES;

    // ---- phase A: hidden = relu(h1b @ mw1t) -> hid LDS (bf16) ----
    {
        int arow = m0 + wv * 16 + l15;
        int arow_c = arow < M ? arow : M - 1;
        const unsigned short* ap = A + (size_t)arow_c * 128 + kg * 8;
        f32x4 acc[16];
#pragma unroll
        for (int nt = 0; nt < 16; ++nt) acc[nt] = (f32x4){0.f, 0.f, 0.f, 0.f};
#pragma unroll
        for (int kidx = 0; kidx < 4; ++kidx) {
            const int ko = kidx * 32;
            short8v af = *(const short8v*)(ap + ko);
#pragma unroll
            for (int nt = 0; nt < 16; ++nt) {
                short8v bf = *(const short8v*)(mw1t + (size_t)(nt * 16 + l15) * 128 + ko + kg * 8);
                acc[nt] = __builtin_amdgcn_mfma_f32_16x16x32_bf16(af, bf, acc[nt], 0, 0, 0);
            }
        }
#pragma unroll
        for (int nt = 0; nt < 16; ++nt) {
#pragma unroll
            for (int r = 0; r < 4; ++r) {
                int row = wv * 16 + kg * 4 + r;
                int col = nt * 16 + l15;
                hid[row * 264 + col] = f2bf(fmaxf(acc[nt][r], 0.f));
            }
        }
    }
    __syncthreads();

    // ---- phase B: out = LN(hid @ mw2t + h1) ----
    {
        const int lrow = wv * 16 + l15;
        f32x4 acc[8];
#pragma unroll
        for (int nt = 0; nt < 8; ++nt) acc[nt] = (f32x4){0.f, 0.f, 0.f, 0.f};
#pragma unroll
        for (int kidx = 0; kidx < 8; ++kidx) {
            const int ko = kidx * 32;
            short8v af = *(const short8v*)&hid[lrow * 264 + ko + kg * 8];
#pragma unroll
            for (int nt = 0; nt < 8; ++nt) {
                short8v bf = *(const short8v*)(mw2t + (size_t)(nt * 16 + l15) * 256 + ko + kg * 8);
                acc[nt] = __builtin_amdgcn_mfma_f32_16x16x32_bf16(af, bf, acc[nt], 0, 0, 0);
            }
        }
        float gv[8], bv[8];
#pragma unroll
        for (int nt = 0; nt < 8; ++nt) {
            gv[nt] = gamma[nt * 16 + l15];
            bv[nt] = beta[nt * 16 + l15];
        }
#pragma unroll
        for (int r = 0; r < 4; ++r) {
            int row = m0 + wv * 16 + kg * 4 + r;
            int rc = row < M ? row : M - 1;
            float x[8];
            float s = 0.f;
#pragma unroll
            for (int nt = 0; nt < 8; ++nt) {
                x[nt] = acc[nt][r] + res[(size_t)rc * 128 + nt * 16 + l15];
                s += x[nt];
            }
#pragma unroll
            for (int off = 1; off < 16; off <<= 1) s += __shfl_xor(s, off);
            float mu = s * (1.f / 128.f);
            float ss = 0.f;
#pragma unroll
            for (int nt = 0; nt < 8; ++nt) {
                float d = x[nt] - mu;
                ss += d * d;
            }
#pragma unroll
            for (int off = 1; off < 16; off <<= 1) ss += __shfl_xor(ss, off);
            float rsv = rsqrtf(ss * (1.f / 128.f) + 1e-5f);
            if (row < M) {
#pragma unroll
                for (int nt = 0; nt < 8; ++nt)
                    out[(size_t)row * 128 + nt * 16 + l15] =
                        (x[nt] - mu) * rsv * gv[nt] + bv[nt];
            }
        }
    }
}

extern "C" void kernel_launch(void* const* d_in, const int* in_sizes, int n_in,
                              void* d_out, int out_size, void* d_ws, size_t ws_size,
                              hipStream_t stream)
{
    const float* h    = (const float*)d_in[0];
    const float* e_ij = (const float*)d_in[1];
    const float* W1   = (const float*)d_in[2];
    const float* W2   = (const float*)d_in[3];
    const float* W3   = (const float*)d_in[4];
    const float* W4   = (const float*)d_in[5];
    const float* W5   = (const float*)d_in[6];
    const float* W6   = (const float*)d_in[7];
    const float* ln_g = (const float*)d_in[8];
    const float* ln_b = (const float*)d_in[9];
    const float* mw1  = (const float*)d_in[10];
    const float* mw2  = (const float*)d_in[11];
    const int*   src  = (const int*)d_in[12];
    const int*   dst  = (const int*)d_in[13];
    float* out = (float*)d_out;

    float* ws = (float*)d_ws;
    // layout (float offsets); P_max = 112640 pieces (N + E/64 rounded up)
    float* hw6f  = ws;                                 // [100k][128]
    float* h1    = ws + 12800000;                      // [100k][128]
    float* dpart = ws + 25600000;                      // [112640][128] = 14,417,920
    float* apart = ws + 40100000;                      // [112640][128]
    unsigned short* uvkb  = (unsigned short*)(ws + 54600000);     // [100k][384]
    unsigned short* h1b   = (unsigned short*)(ws + 73800000);     // [100k][128]
    unsigned short* w3t   = (unsigned short*)(ws + 93000000);     // [128][128]
    unsigned short* w5t   = w3t + 16384;
    unsigned short* wcatt = w5t + 16384;               // [512][128]
    unsigned short* mw1t  = wcatt + 65536;             // [256][128]
    unsigned short* mw2t  = mw1t + 32768;              // [128][256]
    int* ibase    = (int*)(ws + 93100000);
    int* counts   = ibase;                             // [N]
    int* offsets  = ibase + 100000;                    // [N+1]
    int* cursor   = ibase + 200001;                    // [N]
    int* npieces  = ibase + 300001;                    // [N]
    int* ppos     = ibase + 400001;                    // [N+1]
    int* partials = ibase + 500102;                    // [128]
    int* edge_ord = ibase + 500230;                    // [E]
    int* src_ord  = edge_ord + N_EDGES;                // [E]
    int* dst_ord  = src_ord + N_EDGES;                 // [E]

    dim3 blk(256);
    hipMemsetAsync(counts, 0, N_NODES * sizeof(int), stream);

    hist_dst<<<N_EDGES / 256, blk, 0, stream>>>(dst, counts);
    scan_p1<<<98, blk, 0, stream>>>(counts, partials, N_NODES);
    scan_p2<<<1, 64, 0, stream>>>(partials, 98, offsets + N_NODES);
    scan_p3<<<98, blk, 0, stream>>>(counts, offsets, cursor, partials, N_NODES);
    scatter_edges<<<N_EDGES / 256, blk, 0, stream>>>(dst, src, cursor,
                                                     edge_ord, src_ord, dst_ord);
    calc_npieces<<<391, blk, 0, stream>>>(offsets, npieces);
    scan_p1<<<98, blk, 0, stream>>>(npieces, partials, N_NODES);
    scan_p2<<<1, 64, 0, stream>>>(partials, 98, ppos + N_NODES);
    scan_p3<<<98, blk, 0, stream>>>(npieces, ppos, (int*)nullptr, partials, N_NODES);

    prep_weights<<<576, blk, 0, stream>>>(W1, W2, W3, W4, W5, W6, mw1, mw2,
                                          w3t, w5t, wcatt, mw1t, mw2t);

    // u|v|k (bf16) and hw6 (f32) = h @ [W1|W2|W4|W6]  (A staged once, 4 panels)
    gemm_node<<<1563, blk, 0, stream>>>(h, wcatt, uvkb, hw6f);

    edge_agg<<<N_EDGES / 64, blk, 0, stream>>>(e_ij, w3t, w5t, uvkb,
                                               edge_ord, src_ord, dst_ord,
                                               offsets, ppos, dpart, apart);

    node_finalize<<<N_NODES / 4, blk, 0, stream>>>(hw6f, uvkb, dpart, apart, ppos,
                                                   ln_g, ln_b, h1, h1b);

    // fused MLP1 + MLP2 + LN (hidden in LDS; no hiddenb round-trip)
    mlp_tail<<<1563, blk, 0, stream>>>(h1b, h1, mw1t, mw2t, ln_g, ln_b, out);
}